// Round 3
// baseline (892.993 us; speedup 1.0000x reference)
//
#include <hip/hip_runtime.h>
#include <hip/hip_bf16.h>

// ---------- helpers ----------
typedef __bf16 bf16x8 __attribute__((ext_vector_type(8)));
typedef float  f32x4  __attribute__((ext_vector_type(4)));

__device__ __forceinline__ unsigned short f2bf(float f) {
    union { float f; unsigned int u; } v; v.f = f;
    unsigned int u = v.u;
    unsigned int r = (u + 0x7fffu + ((u >> 16) & 1u)) >> 16;   // RNE
    return (unsigned short)r;
}

typedef const __attribute__((address_space(1))) unsigned int* gptr_t;
typedef __attribute__((address_space(3))) unsigned int* lptr_t;
__device__ __forceinline__ void async_ld16(const void* g, void* l) {
    __builtin_amdgcn_global_load_lds((gptr_t)g, (lptr_t)l, 16, 0, 0);
}

// fast GELU (tanh form): max |err| vs exact-erf GELU ~5e-4.
__device__ __forceinline__ float gelu_fast(float x) {
    const float c1 = 2.30223608f;          // 2*sqrt(2/pi)*log2(e)
    const float c2 = 0.102944903f;         // c1 * 0.044715
    float s  = x * x;
    float zn = x * __builtin_fmaf(s, -c2, -c1);
    float u  = __builtin_amdgcn_exp2f(zn);
    return x * __builtin_amdgcn_rcpf(1.0f + u);
}

#define Bn 16384
#define Dd 1024
#define Hh 2048
#define Ee 4
#define Cc 3

// ---------- kernel 1: W1' = diag(ex_ln_g) * W1, transposed to [N=E*H][K=D], bf16 ----------
__global__ void prep_w1(const float* __restrict__ w1, const float* __restrict__ exlng,
                        unsigned short* __restrict__ w1t) {
    __shared__ float tile[64][65];
    const int d0 = blockIdx.x * 64, h0 = blockIdx.y * 64, e = blockIdx.z;
    const int t = threadIdx.x;
    const float* gp = exlng + e * Dd + d0;
    const float* wp = w1 + ((size_t)e * Dd + d0) * Hh + h0;
    #pragma unroll
    for (int j = 0; j < 16; ++j) {
        int idx = t + j * 256; int dl = idx >> 6, hl = idx & 63;
        tile[dl][hl] = wp[(size_t)dl * Hh + hl] * gp[dl];
    }
    __syncthreads();
    #pragma unroll
    for (int j = 0; j < 8; ++j) {
        int idx = t + j * 256; int hl = idx >> 5, k2 = (idx & 31) * 2;
        ushort2 o; o.x = f2bf(tile[k2][hl]); o.y = f2bf(tile[k2 + 1][hl]);
        *(ushort2*)(w1t + ((size_t)(e * Hh + h0 + hl)) * Dd + d0 + k2) = o;
    }
}

// ---------- kernel 2: b1'[n] = b1[e][h] + sum_d ex_ln_b[e][d] * W1[e][d][h] ----------
__global__ void prep_b1(const float* __restrict__ w1, const float* __restrict__ exlnb,
                        const float* __restrict__ b1, float* __restrict__ b1p) {
    const int e = blockIdx.y, h0 = blockIdx.x * 64;
    const int t = threadIdx.x, hl = t & 63, dq = t >> 6;
    float acc = 0.f;
    const float* wp = w1 + ((size_t)e * Dd) * Hh + h0 + hl;
    const float* lb = exlnb + e * Dd;
    for (int d = dq; d < Dd; d += 4)
        acc += lb[d] * wp[(size_t)d * Hh];
    __shared__ float red[4][64];
    red[dq][hl] = acc;
    __syncthreads();
    if (t < 64) {
        float s = red[0][t] + red[1][t] + red[2][t] + red[3][t];
        b1p[e * Hh + h0 + t] = b1[e * Hh + h0 + t] + s;
    }
}

// ---------- kernel 3: normalize + gate softmax + out init (wave-per-row, no LDS) ----------
__global__ __launch_bounds__(256) void norm_gate(
        const float* __restrict__ x,
        const float* __restrict__ gg, const float* __restrict__ gb,
        const float* __restrict__ gw, const float* __restrict__ gbias,
        const float* __restrict__ b2,
        unsigned short* __restrict__ normed,
        float* __restrict__ gate, float* __restrict__ out) {
    const int row  = blockIdx.x * 4 + (threadIdx.x >> 6);
    const int lane = threadIdx.x & 63;
    const float4* xp = (const float4*)(x + (size_t)row * Dd);
    // lane-consecutive float4s: chunk j covers d = j*256 + lane*4 .. +3
    float4 v[4];
    float s = 0.f, q = 0.f;
    #pragma unroll
    for (int j = 0; j < 4; ++j) {
        v[j] = xp[j * 64 + lane];
        s += v[j].x + v[j].y + v[j].z + v[j].w;
        q += v[j].x * v[j].x + v[j].y * v[j].y + v[j].z * v[j].z + v[j].w * v[j].w;
    }
    #pragma unroll
    for (int off = 32; off; off >>= 1) { s += __shfl_xor(s, off); q += __shfl_xor(q, off); }
    const float mu = s * (1.f / Dd);
    const float var = q * (1.f / Dd) - mu * mu;
    const float rstd = rsqrtf(var + 1e-5f);
    float l0 = 0.f, l1 = 0.f, l2 = 0.f, l3 = 0.f;
    #pragma unroll
    for (int j = 0; j < 4; ++j) {
        const int d = j * 256 + lane * 4;
        float n[4] = { (v[j].x - mu) * rstd, (v[j].y - mu) * rstd,
                       (v[j].z - mu) * rstd, (v[j].w - mu) * rstd };
        ushort4 u; u.x = f2bf(n[0]); u.y = f2bf(n[1]); u.z = f2bf(n[2]); u.w = f2bf(n[3]);
        ((ushort4*)(normed + (size_t)row * Dd))[j * 64 + lane] = u;
        float4 g4 = ((const float4*)gg)[j * 64 + lane];
        float4 b4 = ((const float4*)gb)[j * 64 + lane];
        float a[4] = { n[0] * g4.x + b4.x, n[1] * g4.y + b4.y,
                       n[2] * g4.z + b4.z, n[3] * g4.w + b4.w };
        #pragma unroll
        for (int c = 0; c < 4; ++c) {
            float4 wv = ((const float4*)gw)[d + c];
            l0 += a[c] * wv.x; l1 += a[c] * wv.y; l2 += a[c] * wv.z; l3 += a[c] * wv.w;
        }
    }
    #pragma unroll
    for (int off = 32; off; off >>= 1) {
        l0 += __shfl_xor(l0, off); l1 += __shfl_xor(l1, off);
        l2 += __shfl_xor(l2, off); l3 += __shfl_xor(l3, off);
    }
    if (lane == 0) {
        float L0 = l0 + gbias[0], L1 = l1 + gbias[1], L2 = l2 + gbias[2], L3 = l3 + gbias[3];
        float mx = fmaxf(fmaxf(L0, L1), fmaxf(L2, L3));
        float e0 = expf(L0 - mx), e1 = expf(L1 - mx), e2 = expf(L2 - mx), e3 = expf(L3 - mx);
        float inv = 1.f / (e0 + e1 + e2 + e3);
        float g0 = e0 * inv, g1 = e1 * inv, g2 = e2 * inv, g3 = e3 * inv;
        float4 gv; gv.x = g0; gv.y = g1; gv.z = g2; gv.w = g3;
        ((float4*)gate)[row] = gv;
        out[row * 3 + 0] = g0 * b2[0] + g1 * b2[3] + g2 * b2[6] + g3 * b2[9];
        out[row * 3 + 1] = g0 * b2[1] + g1 * b2[4] + g2 * b2[7] + g3 * b2[10];
        out[row * 3 + 2] = g0 * b2[2] + g1 * b2[5] + g2 * b2[8] + g3 * b2[11];
    }
}

// ---------- kernel 4: 256x256 GEMM + GELU + (@W2) + gated atomic add ----------
// v4: single-phase K-tile: {stage(kt+2); 12 ds_read; 32 MFMA; counted vmcnt; ONE barrier}.
//     Hazard-free: reads hit buf[kt&3], stage writes buf[(kt+2)&3], in-flight writes from
//     kt-1 hit buf[(kt+1)&3] -- pairwise distinct mod 4. 4 buffers = 2-tile prefetch lead.
__global__ __launch_bounds__(512, 2) void gemm_fused(
    const unsigned short* __restrict__ A,    // [16384][1024] bf16
    const unsigned short* __restrict__ Bt,   // [8192][1024] bf16 (N-major)
    const float* __restrict__ b1p,           // [8192]
    const float* __restrict__ w2,            // [8192][3]
    const float* __restrict__ gate,          // [16384][4]
    float* __restrict__ out)                 // [16384][3]
{
    __shared__ unsigned short As[4][256 * 32];   // 64 KB
    __shared__ unsigned short Bs[4][256 * 32];   // 64 KB
    __shared__ float w2s[256 * 3];
    __shared__ float b1s[256];

    const int m0 = blockIdx.x * 256;
    const int n0 = blockIdx.y * 256;
    const int t = threadIdx.x, lane = t & 63, wid = t >> 6;
    const int wm = wid >> 2, wn = wid & 3;          // 2 x 4 wave grid
    const int quad = lane >> 4, l15 = lane & 15;

    if (t < 256) {
        b1s[t] = b1p[n0 + t];
        w2s[t * 3 + 0] = w2[(n0 + t) * 3 + 0];
        w2s[t * 3 + 1] = w2[(n0 + t) * 3 + 1];
        w2s[t * 3 + 2] = w2[(n0 + t) * 3 + 2];
    }

    // staging: thread t -> row t>>2 (sweep adds 128), 16B slot (t&3), source col
    // pre-swizzled so LDS[row][slot] = global[row][slot ^ ((row>>1)&3)].
    const int srow  = t >> 2;
    const int sslot = (t & 3) ^ ((t >> 3) & 3);
    const unsigned short* ga = A  + (size_t)(m0 + srow) * Dd + sslot * 8;
    const unsigned short* gb = Bt + (size_t)(n0 + srow) * Dd + sslot * 8;
    const int ldoff = t * 8;                        // elements; sweep 1 adds 4096

#define STAGE_A(kt) { unsigned short* d = &As[(kt) & 3][ldoff];                 \
    async_ld16(ga + (kt) * 32,            d);                                   \
    async_ld16(ga + (kt) * 32 + 128 * Dd, d + 4096); }
#define STAGE_B(kt) { unsigned short* d = &Bs[(kt) & 3][ldoff];                 \
    async_ld16(gb + (kt) * 32,            d);                                   \
    async_ld16(gb + (kt) * 32 + 128 * Dd, d + 4096); }

    f32x4 acc[8][4] = {};

    // fragment read offsets (elements), swizzled to match staging
    const int rsw   = (l15 >> 1) & 3;
    const int aBase = (wm * 128 + l15) * 32 + ((quad ^ rsw) * 8);
    const int bBase = (wn * 64  + l15) * 32 + ((quad ^ rsw) * 8);

    // prologue: stage tiles 0 and 1, wait for tile 0
    STAGE_A(0); STAGE_B(0);
    STAGE_A(1); STAGE_B(1);
    __asm__ volatile("s_waitcnt vmcnt(4)" ::: "memory");
    __syncthreads();

    for (int kt = 0; kt < 32; ++kt) {
        const unsigned short* as = &As[kt & 3][0];
        const unsigned short* bs = &Bs[kt & 3][0];

        if (kt < 30) { STAGE_A(kt + 2); STAGE_B(kt + 2); }

        bf16x8 bf[4], af[8];
        #pragma unroll
        for (int ni = 0; ni < 4; ++ni) bf[ni] = *(const bf16x8*)(bs + bBase + ni * 512);
        #pragma unroll
        for (int mi = 0; mi < 8; ++mi) af[mi] = *(const bf16x8*)(as + aBase + mi * 512);

        __builtin_amdgcn_s_setprio(1);
        #pragma unroll
        for (int mi = 0; mi < 8; ++mi)
            #pragma unroll
            for (int ni = 0; ni < 4; ++ni)
                acc[mi][ni] = __builtin_amdgcn_mfma_f32_16x16x32_bf16(af[mi], bf[ni], acc[mi][ni], 0, 0, 0);
        __builtin_amdgcn_s_setprio(0);

        if (kt < 30) {
            __asm__ volatile("s_waitcnt vmcnt(4)" ::: "memory");  // tile kt+1 landed; kt+2 in flight
        } else {
            __asm__ volatile("s_waitcnt vmcnt(0)" ::: "memory");
        }
        __builtin_amdgcn_s_barrier();
        __builtin_amdgcn_sched_barrier(0);   // nothing (esp. next-tile ds_read) crosses the barrier
    }
#undef STAGE_A
#undef STAGE_B

    // epilogue: h = gelu(acc + b1'), partial logits = h @ w2 (3 cols), gated atomic add
    const int e = n0 >> 11;   // each 256-wide N-tile lies in one expert (H=2048)
    #pragma unroll
    for (int mi = 0; mi < 8; ++mi) {
        float pr[4][3];
        #pragma unroll
        for (int r = 0; r < 4; ++r) { pr[r][0] = 0.f; pr[r][1] = 0.f; pr[r][2] = 0.f; }
        #pragma unroll
        for (int ni = 0; ni < 4; ++ni) {
            const int nl = wn * 64 + ni * 16 + l15;
            const float b1v = b1s[nl];
            const float wa = w2s[nl * 3 + 0], wb = w2s[nl * 3 + 1], wc = w2s[nl * 3 + 2];
            #pragma unroll
            for (int r = 0; r < 4; ++r) {
                float xh = acc[mi][ni][r] + b1v;
                float h = gelu_fast(xh);
                pr[r][0] += h * wa; pr[r][1] += h * wb; pr[r][2] += h * wc;
            }
        }
        #pragma unroll
        for (int off = 1; off < 16; off <<= 1) {
            #pragma unroll
            for (int r = 0; r < 4; ++r) {
                pr[r][0] += __shfl_xor(pr[r][0], off);
                pr[r][1] += __shfl_xor(pr[r][1], off);
                pr[r][2] += __shfl_xor(pr[r][2], off);
            }
        }
        if (l15 == 0) {
            #pragma unroll
            for (int r = 0; r < 4; ++r) {
                const int row = m0 + wm * 128 + mi * 16 + quad * 4 + r;
                const float g = gate[(size_t)row * 4 + e];
                atomicAdd(&out[row * 3 + 0], g * pr[r][0]);
                atomicAdd(&out[row * 3 + 1], g * pr[r][1]);
                atomicAdd(&out[row * 3 + 2], g * pr[r][2]);
            }
        }
    }
}

// ---------- launch ----------
extern "C" void kernel_launch(void* const* d_in, const int* in_sizes, int n_in,
                              void* d_out, int out_size, void* d_ws, size_t ws_size,
                              hipStream_t stream) {
    const float* x     = (const float*)d_in[0];
    const float* gg    = (const float*)d_in[1];
    const float* gb    = (const float*)d_in[2];
    const float* gw    = (const float*)d_in[3];
    const float* gbias = (const float*)d_in[4];
    const float* exlng = (const float*)d_in[5];
    const float* exlnb = (const float*)d_in[6];
    const float* w1    = (const float*)d_in[7];
    const float* b1    = (const float*)d_in[8];
    const float* w2    = (const float*)d_in[9];
    const float* b2    = (const float*)d_in[10];
    float* out = (float*)d_out;

    char* ws = (char*)d_ws;
    unsigned short* normed = (unsigned short*)ws;                         // 16384*1024*2 = 33554432
    unsigned short* w1t    = (unsigned short*)(ws + 33554432);            // 8192*1024*2  = 16777216
    float* b1p  = (float*)(ws + 33554432 + 16777216);                     // 8192*4       = 32768
    float* gate = (float*)(ws + 33554432 + 16777216 + 32768);             // 16384*4*4    = 262144

    prep_w1<<<dim3(16, 32, 4), 256, 0, stream>>>(w1, exlng, w1t);
    prep_b1<<<dim3(32, 4), 256, 0, stream>>>(w1, exlnb, b1, b1p);
    norm_gate<<<4096, 256, 0, stream>>>(x, gg, gb, gw, gbias, b2, normed, gate, out);
    gemm_fused<<<dim3(64, 32), 512, 0, stream>>>(normed, w1t, b1p, w2, gate, out);
}

// Round 4
// 683.345 us; speedup vs baseline: 1.3068x; 1.3068x over previous
//
#include <hip/hip_runtime.h>
#include <hip/hip_bf16.h>

// ---------- helpers ----------
typedef __bf16 bf16x8 __attribute__((ext_vector_type(8)));
typedef float  f32x4  __attribute__((ext_vector_type(4)));

__device__ __forceinline__ unsigned short f2bf(float f) {
    union { float f; unsigned int u; } v; v.f = f;
    unsigned int u = v.u;
    unsigned int r = (u + 0x7fffu + ((u >> 16) & 1u)) >> 16;   // RNE
    return (unsigned short)r;
}

typedef const __attribute__((address_space(1))) unsigned int* gptr_t;
typedef __attribute__((address_space(3))) unsigned int* lptr_t;
__device__ __forceinline__ void async_ld16(const void* g, void* l) {
    __builtin_amdgcn_global_load_lds((gptr_t)g, (lptr_t)l, 16, 0, 0);
}

// fast GELU (tanh form): max |err| vs exact-erf GELU ~5e-4.
__device__ __forceinline__ float gelu_fast(float x) {
    const float c1 = 2.30223608f;          // 2*sqrt(2/pi)*log2(e)
    const float c2 = 0.102944903f;         // c1 * 0.044715
    float s  = x * x;
    float zn = x * __builtin_fmaf(s, -c2, -c1);
    float u  = __builtin_amdgcn_exp2f(zn);
    return x * __builtin_amdgcn_rcpf(1.0f + u);
}

#define Bn 16384
#define Dd 1024
#define Hh 2048
#define Ee 4
#define Cc 3

// ---------- kernel 0: b1p = b1 (init before prep_w1 accumulates into it) ----------
__global__ void init_b1(const float* __restrict__ b1, float* __restrict__ b1p) {
    int i = blockIdx.x * 256 + threadIdx.x;
    b1p[i] = b1[i];
}

// ---------- kernel 1: W1' = diag(ex_ln_g)*W1 transposed to [N][K] bf16,
//                      PLUS bias partials b1p[n] += sum_d ex_ln_b[d]*W1[d][h] ----------
__global__ void prep_w1(const float* __restrict__ w1, const float* __restrict__ exlng,
                        const float* __restrict__ exlnb,
                        unsigned short* __restrict__ w1t, float* __restrict__ b1p) {
    __shared__ float tile[64][65];
    __shared__ float red[4][64];
    const int d0 = blockIdx.x * 64, h0 = blockIdx.y * 64, e = blockIdx.z;
    const int t = threadIdx.x;
    const float* gp = exlng + e * Dd + d0;
    const float* lb = exlnb + e * Dd + d0;
    const float* wp = w1 + ((size_t)e * Dd + d0) * Hh + h0;
    #pragma unroll
    for (int j = 0; j < 16; ++j) {
        int idx = t + j * 256; int dl = idx >> 6, hl = idx & 63;
        tile[dl][hl] = wp[(size_t)dl * Hh + hl];     // raw W (gain applied at write-out)
    }
    __syncthreads();
    // transposed, gain-scaled bf16 write
    #pragma unroll
    for (int j = 0; j < 8; ++j) {
        int idx = t + j * 256; int hl = idx >> 5, k2 = (idx & 31) * 2;
        ushort2 o; o.x = f2bf(tile[k2][hl] * gp[k2]); o.y = f2bf(tile[k2 + 1][hl] * gp[k2 + 1]);
        *(ushort2*)(w1t + ((size_t)(e * Hh + h0 + hl)) * Dd + d0 + k2) = o;
    }
    // bias partial: sum over this block's 64 d of lb[d]*w[d][h]
    const int hl = t & 63, dq = t >> 6;
    float acc = 0.f;
    #pragma unroll
    for (int i = 0; i < 16; ++i)
        acc += lb[dq * 16 + i] * tile[dq * 16 + i][hl];
    red[dq][hl] = acc;
    __syncthreads();
    if (t < 64) {
        float s = red[0][t] + red[1][t] + red[2][t] + red[3][t];
        atomicAdd(&b1p[e * Hh + h0 + t], s);
    }
}

// ---------- kernel 3: normalize + gate softmax + out init (wave-per-row, no LDS) ----------
__global__ __launch_bounds__(256) void norm_gate(
        const float* __restrict__ x,
        const float* __restrict__ gg, const float* __restrict__ gb,
        const float* __restrict__ gw, const float* __restrict__ gbias,
        const float* __restrict__ b2,
        unsigned short* __restrict__ normed,
        float* __restrict__ gate, float* __restrict__ out) {
    const int row  = blockIdx.x * 4 + (threadIdx.x >> 6);
    const int lane = threadIdx.x & 63;
    const float4* xp = (const float4*)(x + (size_t)row * Dd);
    float4 v[4];
    float s = 0.f, q = 0.f;
    #pragma unroll
    for (int j = 0; j < 4; ++j) {
        v[j] = xp[j * 64 + lane];
        s += v[j].x + v[j].y + v[j].z + v[j].w;
        q += v[j].x * v[j].x + v[j].y * v[j].y + v[j].z * v[j].z + v[j].w * v[j].w;
    }
    #pragma unroll
    for (int off = 32; off; off >>= 1) { s += __shfl_xor(s, off); q += __shfl_xor(q, off); }
    const float mu = s * (1.f / Dd);
    const float var = q * (1.f / Dd) - mu * mu;
    const float rstd = rsqrtf(var + 1e-5f);
    float l0 = 0.f, l1 = 0.f, l2 = 0.f, l3 = 0.f;
    #pragma unroll
    for (int j = 0; j < 4; ++j) {
        const int d = j * 256 + lane * 4;
        float n[4] = { (v[j].x - mu) * rstd, (v[j].y - mu) * rstd,
                       (v[j].z - mu) * rstd, (v[j].w - mu) * rstd };
        ushort4 u; u.x = f2bf(n[0]); u.y = f2bf(n[1]); u.z = f2bf(n[2]); u.w = f2bf(n[3]);
        ((ushort4*)(normed + (size_t)row * Dd))[j * 64 + lane] = u;
        float4 g4 = ((const float4*)gg)[j * 64 + lane];
        float4 b4 = ((const float4*)gb)[j * 64 + lane];
        float a[4] = { n[0] * g4.x + b4.x, n[1] * g4.y + b4.y,
                       n[2] * g4.z + b4.z, n[3] * g4.w + b4.w };
        #pragma unroll
        for (int c = 0; c < 4; ++c) {
            float4 wv = ((const float4*)gw)[d + c];
            l0 += a[c] * wv.x; l1 += a[c] * wv.y; l2 += a[c] * wv.z; l3 += a[c] * wv.w;
        }
    }
    #pragma unroll
    for (int off = 32; off; off >>= 1) {
        l0 += __shfl_xor(l0, off); l1 += __shfl_xor(l1, off);
        l2 += __shfl_xor(l2, off); l3 += __shfl_xor(l3, off);
    }
    if (lane == 0) {
        float L0 = l0 + gbias[0], L1 = l1 + gbias[1], L2 = l2 + gbias[2], L3 = l3 + gbias[3];
        float mx = fmaxf(fmaxf(L0, L1), fmaxf(L2, L3));
        float e0 = expf(L0 - mx), e1 = expf(L1 - mx), e2 = expf(L2 - mx), e3 = expf(L3 - mx);
        float inv = 1.f / (e0 + e1 + e2 + e3);
        float g0 = e0 * inv, g1 = e1 * inv, g2 = e2 * inv, g3 = e3 * inv;
        float4 gv; gv.x = g0; gv.y = g1; gv.z = g2; gv.w = g3;
        ((float4*)gate)[row] = gv;
        out[row * 3 + 0] = g0 * b2[0] + g1 * b2[3] + g2 * b2[6] + g3 * b2[9];
        out[row * 3 + 1] = g0 * b2[1] + g1 * b2[4] + g2 * b2[7] + g3 * b2[10];
        out[row * 3 + 2] = g0 * b2[2] + g1 * b2[5] + g2 * b2[8] + g3 * b2[11];
    }
}

// ---------- kernel 4: 256x256 GEMM + GELU + (@W2) + gated atomic add ----------
// v5: ONE barrier + ONE counted vmcnt per K-tile, zero lgkm drains.
//     Per tile: [12 ds_read (buf confirmed last tile)] [stage kt+2: 4 gload_lds]
//               [vmcnt(4)] [s_barrier] [sched_barrier(0xF): DS/VMEM pinned, ALU free]
//               [setprio1; 32 MFMA; setprio0].
//     Ledger (per-thread, 4 loads/tile): after stage, outstanding = (kt+1)'s 4 + (kt+2)'s 4;
//     vmcnt(4) waits (kt+1) -- issued one full tile (~3000 cyc) earlier: zero-stall.
//     Buffers mod 4: read kt, write kt+2, in-flight kt+1 -- pairwise distinct; skew <1 tile.
__global__ __launch_bounds__(512, 2) void gemm_fused(
    const unsigned short* __restrict__ A,    // [16384][1024] bf16
    const unsigned short* __restrict__ Bt,   // [8192][1024] bf16 (N-major)
    const float* __restrict__ b1p,           // [8192]
    const float* __restrict__ w2,            // [8192][3]
    const float* __restrict__ gate,          // [16384][4]
    float* __restrict__ out)                 // [16384][3]
{
    __shared__ unsigned short As[4][256 * 32];   // 64 KB
    __shared__ unsigned short Bs[4][256 * 32];   // 64 KB
    __shared__ float w2s[256 * 3];
    __shared__ float b1s[256];

    const int m0 = blockIdx.x * 256;
    const int n0 = blockIdx.y * 256;
    const int t = threadIdx.x, lane = t & 63, wid = t >> 6;
    const int wm = wid >> 2, wn = wid & 3;          // 2 x 4 wave grid
    const int quad = lane >> 4, l15 = lane & 15;

    if (t < 256) {
        b1s[t] = b1p[n0 + t];
        w2s[t * 3 + 0] = w2[(n0 + t) * 3 + 0];
        w2s[t * 3 + 1] = w2[(n0 + t) * 3 + 1];
        w2s[t * 3 + 2] = w2[(n0 + t) * 3 + 2];
    }

    // staging: thread t -> row t>>2 (sweep adds 128), 16B slot (t&3), source col
    // pre-swizzled so LDS[row][slot] = global[row][slot ^ ((row>>1)&3)].
    const int srow  = t >> 2;
    const int sslot = (t & 3) ^ ((t >> 3) & 3);
    const unsigned short* ga = A  + (size_t)(m0 + srow) * Dd + sslot * 8;
    const unsigned short* gb = Bt + (size_t)(n0 + srow) * Dd + sslot * 8;
    const int ldoff = t * 8;                        // elements; sweep 1 adds 4096

#define STAGE_A(kt) { unsigned short* d = &As[(kt) & 3][ldoff];                 \
    async_ld16(ga + (kt) * 32,            d);                                   \
    async_ld16(ga + (kt) * 32 + 128 * Dd, d + 4096); }
#define STAGE_B(kt) { unsigned short* d = &Bs[(kt) & 3][ldoff];                 \
    async_ld16(gb + (kt) * 32,            d);                                   \
    async_ld16(gb + (kt) * 32 + 128 * Dd, d + 4096); }

    f32x4 acc[8][4] = {};

    // fragment read offsets (elements), swizzled to match staging
    const int rsw   = (l15 >> 1) & 3;
    const int aBase = (wm * 128 + l15) * 32 + ((quad ^ rsw) * 8);
    const int bBase = (wn * 64  + l15) * 32 + ((quad ^ rsw) * 8);

    // prologue: stage tiles 0 and 1; full drain once (cheap, amortized over K)
    STAGE_A(0); STAGE_B(0);
    STAGE_A(1); STAGE_B(1);
    __syncthreads();   // vmcnt(0)+lgkm(0)+barrier: tiles 0,1 landed & visible

    for (int kt = 0; kt < 32; ++kt) {
        const unsigned short* as = &As[kt & 3][0];
        const unsigned short* bs = &Bs[kt & 3][0];

        // reads of tile kt (confirmed at previous tile's barrier)
        bf16x8 bf[4], af[8];
        #pragma unroll
        for (int ni = 0; ni < 4; ++ni) bf[ni] = *(const bf16x8*)(bs + bBase + ni * 512);
        #pragma unroll
        for (int mi = 0; mi < 8; ++mi) af[mi] = *(const bf16x8*)(as + aBase + mi * 512);

        // stage tile kt+2 into free buffer
        if (kt < 30) { STAGE_A(kt + 2); STAGE_B(kt + 2); }

        // counted wait: tile kt+1 landed, tile kt+2 in flight; then converge
        if (kt < 30) {
            __asm__ volatile("s_waitcnt vmcnt(4)" ::: "memory");
        } else {
            __asm__ volatile("s_waitcnt vmcnt(0)" ::: "memory");
        }
        __builtin_amdgcn_s_barrier();
        // pin DS/VMEM below the barrier (no hoisting of next-tile reads); ALU/MFMA free
        __builtin_amdgcn_sched_barrier(0xF);

        __builtin_amdgcn_s_setprio(1);
        #pragma unroll
        for (int mi = 0; mi < 8; ++mi)
            #pragma unroll
            for (int ni = 0; ni < 4; ++ni)
                acc[mi][ni] = __builtin_amdgcn_mfma_f32_16x16x32_bf16(af[mi], bf[ni], acc[mi][ni], 0, 0, 0);
        __builtin_amdgcn_s_setprio(0);
    }
#undef STAGE_A
#undef STAGE_B

    // epilogue: h = gelu(acc + b1'), partial logits = h @ w2 (3 cols), gated atomic add
    const int e = n0 >> 11;   // each 256-wide N-tile lies in one expert (H=2048)
    #pragma unroll
    for (int mi = 0; mi < 8; ++mi) {
        float pr[4][3];
        #pragma unroll
        for (int r = 0; r < 4; ++r) { pr[r][0] = 0.f; pr[r][1] = 0.f; pr[r][2] = 0.f; }
        #pragma unroll
        for (int ni = 0; ni < 4; ++ni) {
            const int nl = wn * 64 + ni * 16 + l15;
            const float b1v = b1s[nl];
            const float wa = w2s[nl * 3 + 0], wb = w2s[nl * 3 + 1], wc = w2s[nl * 3 + 2];
            #pragma unroll
            for (int r = 0; r < 4; ++r) {
                float xh = acc[mi][ni][r] + b1v;
                float h = gelu_fast(xh);
                pr[r][0] += h * wa; pr[r][1] += h * wb; pr[r][2] += h * wc;
            }
        }
        #pragma unroll
        for (int off = 1; off < 16; off <<= 1) {
            #pragma unroll
            for (int r = 0; r < 4; ++r) {
                pr[r][0] += __shfl_xor(pr[r][0], off);
                pr[r][1] += __shfl_xor(pr[r][1], off);
                pr[r][2] += __shfl_xor(pr[r][2], off);
            }
        }
        if (l15 == 0) {
            #pragma unroll
            for (int r = 0; r < 4; ++r) {
                const int row = m0 + wm * 128 + mi * 16 + quad * 4 + r;
                const float g = gate[(size_t)row * 4 + e];
                atomicAdd(&out[row * 3 + 0], g * pr[r][0]);
                atomicAdd(&out[row * 3 + 1], g * pr[r][1]);
                atomicAdd(&out[row * 3 + 2], g * pr[r][2]);
            }
        }
    }
}

// ---------- launch ----------
extern "C" void kernel_launch(void* const* d_in, const int* in_sizes, int n_in,
                              void* d_out, int out_size, void* d_ws, size_t ws_size,
                              hipStream_t stream) {
    const float* x     = (const float*)d_in[0];
    const float* gg    = (const float*)d_in[1];
    const float* gb    = (const float*)d_in[2];
    const float* gw    = (const float*)d_in[3];
    const float* gbias = (const float*)d_in[4];
    const float* exlng = (const float*)d_in[5];
    const float* exlnb = (const float*)d_in[6];
    const float* w1    = (const float*)d_in[7];
    const float* b1    = (const float*)d_in[8];
    const float* w2    = (const float*)d_in[9];
    const float* b2    = (const float*)d_in[10];
    float* out = (float*)d_out;

    char* ws = (char*)d_ws;
    unsigned short* normed = (unsigned short*)ws;                         // 16384*1024*2 = 33554432
    unsigned short* w1t    = (unsigned short*)(ws + 33554432);            // 8192*1024*2  = 16777216
    float* b1p  = (float*)(ws + 33554432 + 16777216);                     // 8192*4       = 32768
    float* gate = (float*)(ws + 33554432 + 16777216 + 32768);             // 16384*4*4    = 262144

    init_b1<<<32, 256, 0, stream>>>(b1, b1p);
    prep_w1<<<dim3(16, 32, 4), 256, 0, stream>>>(w1, exlng, exlnb, w1t, b1p);
    norm_gate<<<4096, 256, 0, stream>>>(x, gg, gb, gw, gbias, b2, normed, gate, out);
    gemm_fused<<<dim3(64, 32), 512, 0, stream>>>(normed, w1t, b1p, w2, gate, out);
}

// Round 6
// 487.592 us; speedup vs baseline: 1.8314x; 1.4015x over previous
//
#include <hip/hip_runtime.h>
#include <hip/hip_bf16.h>

// ---------- helpers ----------
typedef __bf16 bf16x8 __attribute__((ext_vector_type(8)));
typedef float  f32x4  __attribute__((ext_vector_type(4)));

__device__ __forceinline__ unsigned short f2bf(float f) {
    union { float f; unsigned int u; } v; v.f = f;
    unsigned int u = v.u;
    unsigned int r = (u + 0x7fffu + ((u >> 16) & 1u)) >> 16;   // RNE
    return (unsigned short)r;
}

typedef const __attribute__((address_space(1))) unsigned int* gptr_t;
typedef __attribute__((address_space(3))) unsigned int* lptr_t;
__device__ __forceinline__ void async_ld16(const void* g, void* l) {
    __builtin_amdgcn_global_load_lds((gptr_t)g, (lptr_t)l, 16, 0, 0);
}

// fast GELU (tanh form): max |err| vs exact-erf GELU ~5e-4.
__device__ __forceinline__ float gelu_fast(float x) {
    const float c1 = 2.30223608f;          // 2*sqrt(2/pi)*log2(e)
    const float c2 = 0.102944903f;         // c1 * 0.044715
    float s  = x * x;
    float zn = x * __builtin_fmaf(s, -c2, -c1);
    float u  = __builtin_amdgcn_exp2f(zn);
    return x * __builtin_amdgcn_rcpf(1.0f + u);
}

#define Bn 16384
#define Dd 1024
#define Hh 2048
#define Ee 4
#define Cc 3

// ---------- kernel 0: b1p = b1 (init before prep_w1 accumulates into it) ----------
__global__ void init_b1(const float* __restrict__ b1, float* __restrict__ b1p) {
    int i = blockIdx.x * 256 + threadIdx.x;
    b1p[i] = b1[i];
}

// ---------- kernel 1: W1' = diag(ex_ln_g)*W1 transposed to [N][K] bf16,
//                      PLUS bias partials b1p[n] += sum_d ex_ln_b[d]*W1[d][h] ----------
__global__ void prep_w1(const float* __restrict__ w1, const float* __restrict__ exlng,
                        const float* __restrict__ exlnb,
                        unsigned short* __restrict__ w1t, float* __restrict__ b1p) {
    __shared__ float tile[64][65];
    __shared__ float red[4][64];
    const int d0 = blockIdx.x * 64, h0 = blockIdx.y * 64, e = blockIdx.z;
    const int t = threadIdx.x;
    const float* gp = exlng + e * Dd + d0;
    const float* lb = exlnb + e * Dd + d0;
    const float* wp = w1 + ((size_t)e * Dd + d0) * Hh + h0;
    #pragma unroll
    for (int j = 0; j < 16; ++j) {
        int idx = t + j * 256; int dl = idx >> 6, hl = idx & 63;
        tile[dl][hl] = wp[(size_t)dl * Hh + hl];     // raw W (gain applied at write-out)
    }
    __syncthreads();
    // transposed, gain-scaled bf16 write
    #pragma unroll
    for (int j = 0; j < 8; ++j) {
        int idx = t + j * 256; int hl = idx >> 5, k2 = (idx & 31) * 2;
        ushort2 o; o.x = f2bf(tile[k2][hl] * gp[k2]); o.y = f2bf(tile[k2 + 1][hl] * gp[k2 + 1]);
        *(ushort2*)(w1t + ((size_t)(e * Hh + h0 + hl)) * Dd + d0 + k2) = o;
    }
    // bias partial: sum over this block's 64 d of lb[d]*w[d][h]
    const int hl = t & 63, dq = t >> 6;
    float acc = 0.f;
    #pragma unroll
    for (int i = 0; i < 16; ++i)
        acc += lb[dq * 16 + i] * tile[dq * 16 + i][hl];
    red[dq][hl] = acc;
    __syncthreads();
    if (t < 64) {
        float s = red[0][t] + red[1][t] + red[2][t] + red[3][t];
        atomicAdd(&b1p[e * Hh + h0 + t], s);
    }
}

// ---------- kernel 3: normalize + gate softmax (wave-per-row, no LDS) ----------
__global__ __launch_bounds__(256) void norm_gate(
        const float* __restrict__ x,
        const float* __restrict__ gg, const float* __restrict__ gb,
        const float* __restrict__ gw, const float* __restrict__ gbias,
        unsigned short* __restrict__ normed,
        float* __restrict__ gate) {
    const int row  = blockIdx.x * 4 + (threadIdx.x >> 6);
    const int lane = threadIdx.x & 63;
    const float4* xp = (const float4*)(x + (size_t)row * Dd);
    float4 v[4];
    float s = 0.f, q = 0.f;
    #pragma unroll
    for (int j = 0; j < 4; ++j) {
        v[j] = xp[j * 64 + lane];
        s += v[j].x + v[j].y + v[j].z + v[j].w;
        q += v[j].x * v[j].x + v[j].y * v[j].y + v[j].z * v[j].z + v[j].w * v[j].w;
    }
    #pragma unroll
    for (int off = 32; off; off >>= 1) { s += __shfl_xor(s, off); q += __shfl_xor(q, off); }
    const float mu = s * (1.f / Dd);
    const float var = q * (1.f / Dd) - mu * mu;
    const float rstd = rsqrtf(var + 1e-5f);
    float l0 = 0.f, l1 = 0.f, l2 = 0.f, l3 = 0.f;
    #pragma unroll
    for (int j = 0; j < 4; ++j) {
        const int d = j * 256 + lane * 4;
        float n[4] = { (v[j].x - mu) * rstd, (v[j].y - mu) * rstd,
                       (v[j].z - mu) * rstd, (v[j].w - mu) * rstd };
        ushort4 u; u.x = f2bf(n[0]); u.y = f2bf(n[1]); u.z = f2bf(n[2]); u.w = f2bf(n[3]);
        ((ushort4*)(normed + (size_t)row * Dd))[j * 64 + lane] = u;
        float4 g4 = ((const float4*)gg)[j * 64 + lane];
        float4 b4 = ((const float4*)gb)[j * 64 + lane];
        float a[4] = { n[0] * g4.x + b4.x, n[1] * g4.y + b4.y,
                       n[2] * g4.z + b4.z, n[3] * g4.w + b4.w };
        #pragma unroll
        for (int c = 0; c < 4; ++c) {
            float4 wv = ((const float4*)gw)[d + c];
            l0 += a[c] * wv.x; l1 += a[c] * wv.y; l2 += a[c] * wv.z; l3 += a[c] * wv.w;
        }
    }
    #pragma unroll
    for (int off = 32; off; off >>= 1) {
        l0 += __shfl_xor(l0, off); l1 += __shfl_xor(l1, off);
        l2 += __shfl_xor(l2, off); l3 += __shfl_xor(l3, off);
    }
    if (lane == 0) {
        float L0 = l0 + gbias[0], L1 = l1 + gbias[1], L2 = l2 + gbias[2], L3 = l3 + gbias[3];
        float mx = fmaxf(fmaxf(L0, L1), fmaxf(L2, L3));
        float e0 = expf(L0 - mx), e1 = expf(L1 - mx), e2 = expf(L2 - mx), e3 = expf(L3 - mx);
        float inv = 1.f / (e0 + e1 + e2 + e3);
        float4 gv; gv.x = e0 * inv; gv.y = e1 * inv; gv.z = e2 * inv; gv.w = e3 * inv;
        ((float4*)gate)[row] = gv;
    }
}

// ---------- kernel 4: 256x256 GEMM + GELU + (@W2) -> per-Nblock partial stores ----------
// v7: K-loop identical to v5. Epilogue: per-wave partials -> LDS reduce ACROSS the 4 wn
//     waves (v6 bug: they overwrote each other) -> ONE plain store per row per block.
//     No device-scope atomics in the hot path.
__global__ __launch_bounds__(512, 2) void gemm_fused(
    const unsigned short* __restrict__ A,    // [16384][1024] bf16
    const unsigned short* __restrict__ Bt,   // [8192][1024] bf16 (N-major)
    const float* __restrict__ b1p,           // [8192]
    const float* __restrict__ w2,            // [8192][3]
    float* __restrict__ part)                // [16384][32][3]
{
    __shared__ unsigned short As[4][256 * 32];   // 64 KB
    __shared__ unsigned short Bs[4][256 * 32];   // 64 KB
    __shared__ float w2s[256 * 3];
    __shared__ float b1s[256];

    const int m0 = blockIdx.x * 256;
    const int nb = blockIdx.y;
    const int n0 = nb * 256;
    const int t = threadIdx.x, lane = t & 63, wid = t >> 6;
    const int wm = wid >> 2, wn = wid & 3;          // 2 x 4 wave grid
    const int quad = lane >> 4, l15 = lane & 15;

    if (t < 256) {
        b1s[t] = b1p[n0 + t];
        w2s[t * 3 + 0] = w2[(n0 + t) * 3 + 0];
        w2s[t * 3 + 1] = w2[(n0 + t) * 3 + 1];
        w2s[t * 3 + 2] = w2[(n0 + t) * 3 + 2];
    }

    // staging: thread t -> row t>>2 (sweep adds 128), 16B slot (t&3), source col
    // pre-swizzled so LDS[row][slot] = global[row][slot ^ ((row>>1)&3)].
    const int srow  = t >> 2;
    const int sslot = (t & 3) ^ ((t >> 3) & 3);
    const unsigned short* ga = A  + (size_t)(m0 + srow) * Dd + sslot * 8;
    const unsigned short* gb = Bt + (size_t)(n0 + srow) * Dd + sslot * 8;
    const int ldoff = t * 8;                        // elements; sweep 1 adds 4096

#define STAGE_A(kt) { unsigned short* d = &As[(kt) & 3][ldoff];                 \
    async_ld16(ga + (kt) * 32,            d);                                   \
    async_ld16(ga + (kt) * 32 + 128 * Dd, d + 4096); }
#define STAGE_B(kt) { unsigned short* d = &Bs[(kt) & 3][ldoff];                 \
    async_ld16(gb + (kt) * 32,            d);                                   \
    async_ld16(gb + (kt) * 32 + 128 * Dd, d + 4096); }

    f32x4 acc[8][4] = {};

    // fragment read offsets (elements), swizzled to match staging
    const int rsw   = (l15 >> 1) & 3;
    const int aBase = (wm * 128 + l15) * 32 + ((quad ^ rsw) * 8);
    const int bBase = (wn * 64  + l15) * 32 + ((quad ^ rsw) * 8);

    // prologue: stage tiles 0 and 1; full drain once (cheap, amortized over K)
    STAGE_A(0); STAGE_B(0);
    STAGE_A(1); STAGE_B(1);
    __syncthreads();   // vmcnt(0)+lgkm(0)+barrier: tiles 0,1 landed & visible

    for (int kt = 0; kt < 32; ++kt) {
        const unsigned short* as = &As[kt & 3][0];
        const unsigned short* bs = &Bs[kt & 3][0];

        // reads of tile kt (confirmed at previous tile's barrier)
        bf16x8 bf[4], af[8];
        #pragma unroll
        for (int ni = 0; ni < 4; ++ni) bf[ni] = *(const bf16x8*)(bs + bBase + ni * 512);
        #pragma unroll
        for (int mi = 0; mi < 8; ++mi) af[mi] = *(const bf16x8*)(as + aBase + mi * 512);

        // stage tile kt+2 into free buffer
        if (kt < 30) { STAGE_A(kt + 2); STAGE_B(kt + 2); }

        // counted wait: tile kt+1 landed, tile kt+2 in flight; then converge
        if (kt < 30) {
            __asm__ volatile("s_waitcnt vmcnt(4)" ::: "memory");
        } else {
            __asm__ volatile("s_waitcnt vmcnt(0)" ::: "memory");
        }
        __builtin_amdgcn_s_barrier();
        // pin DS/VMEM below the barrier (no hoisting of next-tile reads); ALU/MFMA free
        __builtin_amdgcn_sched_barrier(0xF);

        __builtin_amdgcn_s_setprio(1);
        #pragma unroll
        for (int mi = 0; mi < 8; ++mi)
            #pragma unroll
            for (int ni = 0; ni < 4; ++ni)
                acc[mi][ni] = __builtin_amdgcn_mfma_f32_16x16x32_bf16(af[mi], bf[ni], acc[mi][ni], 0, 0, 0);
        __builtin_amdgcn_s_setprio(0);
    }
#undef STAGE_A
#undef STAGE_B

    // epilogue: h = gelu(acc + b1'), partial logits = h @ w2 (3 cols);
    // LDS-reduce over the 4 wn waves, then one plain store per row.
    __syncthreads();                          // all K-loop LDS reads done; reuse As
    float* redb = (float*)&As[0][0];          // [256 rows][4 wn][3] = 12 KB

    #pragma unroll
    for (int mi = 0; mi < 8; ++mi) {
        float pr[4][3];
        #pragma unroll
        for (int r = 0; r < 4; ++r) { pr[r][0] = 0.f; pr[r][1] = 0.f; pr[r][2] = 0.f; }
        #pragma unroll
        for (int ni = 0; ni < 4; ++ni) {
            const int nl = wn * 64 + ni * 16 + l15;
            const float b1v = b1s[nl];
            const float wa = w2s[nl * 3 + 0], wb = w2s[nl * 3 + 1], wc = w2s[nl * 3 + 2];
            #pragma unroll
            for (int r = 0; r < 4; ++r) {
                float xh = acc[mi][ni][r] + b1v;
                float h = gelu_fast(xh);
                pr[r][0] += h * wa; pr[r][1] += h * wb; pr[r][2] += h * wc;
            }
        }
        #pragma unroll
        for (int off = 1; off < 16; off <<= 1) {
            #pragma unroll
            for (int r = 0; r < 4; ++r) {
                pr[r][0] += __shfl_xor(pr[r][0], off);
                pr[r][1] += __shfl_xor(pr[r][1], off);
                pr[r][2] += __shfl_xor(pr[r][2], off);
            }
        }
        if (l15 == 0) {
            #pragma unroll
            for (int r = 0; r < 4; ++r) {
                const int rl = wm * 128 + mi * 16 + quad * 4 + r;   // row within block
                float* rb = redb + (rl * 4 + wn) * 3;
                rb[0] = pr[r][0]; rb[1] = pr[r][1]; rb[2] = pr[r][2];
            }
        }
    }
    __syncthreads();
    if (t < 256) {
        const float* rb = redb + t * 12;
        float o0 = rb[0] + rb[3] + rb[6] + rb[9];
        float o1 = rb[1] + rb[4] + rb[7] + rb[10];
        float o2 = rb[2] + rb[5] + rb[8] + rb[11];
        float* pp = part + (size_t)(m0 + t) * 96 + nb * 3;
        pp[0] = o0; pp[1] = o1; pp[2] = o2;
    }
}

// ---------- kernel 5: out[row] = sum_nb gate[row][nb>>3] * part[row][nb] + gate.b2 ----------
__global__ __launch_bounds__(256) void reduce_out(
        const float* __restrict__ part, const float* __restrict__ gate,
        const float* __restrict__ b2, float* __restrict__ out) {
    const int row = blockIdx.x * 256 + threadIdx.x;
    const float4 gv = ((const float4*)gate)[row];
    const float g[4] = { gv.x, gv.y, gv.z, gv.w };
    float o0 = g[0] * b2[0] + g[1] * b2[3] + g[2] * b2[6] + g[3] * b2[9];
    float o1 = g[0] * b2[1] + g[1] * b2[4] + g[2] * b2[7] + g[3] * b2[10];
    float o2 = g[0] * b2[2] + g[1] * b2[5] + g[2] * b2[8] + g[3] * b2[11];
    const float* pp = part + (size_t)row * 96;
    #pragma unroll
    for (int nb = 0; nb < 32; ++nb) {
        const float ge = g[nb >> 3];
        o0 += ge * pp[nb * 3 + 0];
        o1 += ge * pp[nb * 3 + 1];
        o2 += ge * pp[nb * 3 + 2];
    }
    out[row * 3 + 0] = o0; out[row * 3 + 1] = o1; out[row * 3 + 2] = o2;
}

// ---------- launch ----------
extern "C" void kernel_launch(void* const* d_in, const int* in_sizes, int n_in,
                              void* d_out, int out_size, void* d_ws, size_t ws_size,
                              hipStream_t stream) {
    const float* x     = (const float*)d_in[0];
    const float* gg    = (const float*)d_in[1];
    const float* gb    = (const float*)d_in[2];
    const float* gw    = (const float*)d_in[3];
    const float* gbias = (const float*)d_in[4];
    const float* exlng = (const float*)d_in[5];
    const float* exlnb = (const float*)d_in[6];
    const float* w1    = (const float*)d_in[7];
    const float* b1    = (const float*)d_in[8];
    const float* w2    = (const float*)d_in[9];
    const float* b2    = (const float*)d_in[10];
    float* out = (float*)d_out;

    char* ws = (char*)d_ws;
    unsigned short* normed = (unsigned short*)ws;                         // 16384*1024*2 = 33554432
    unsigned short* w1t    = (unsigned short*)(ws + 33554432);            // 8192*1024*2  = 16777216
    float* b1p  = (float*)(ws + 33554432 + 16777216);                     // 8192*4       = 32768
    float* gate = (float*)(ws + 33554432 + 16777216 + 32768);             // 16384*4*4    = 262144
    float* part = (float*)(ws + 33554432 + 16777216 + 32768 + 262144);    // 16384*32*3*4 = 6291456

    init_b1<<<32, 256, 0, stream>>>(b1, b1p);
    prep_w1<<<dim3(16, 32, 4), 256, 0, stream>>>(w1, exlng, exlnb, w1t, b1p);
    norm_gate<<<4096, 256, 0, stream>>>(x, gg, gb, gw, gbias, normed, gate);
    gemm_fused<<<dim3(64, 32), 512, 0, stream>>>(normed, w1t, b1p, w2, part);
    reduce_out<<<64, 256, 0, stream>>>(part, gate, b2, out);
}